// Round 4
// baseline (561.316 us; speedup 1.0000x reference)
//
#include <hip/hip_runtime.h>

#define NROWS 65536
#define DIN   784
#define NF    10
#define NL    62
#define NSTAT 65
#define NB    1024          // passA grid = partials per stat
#define ROWS_PB 64
#define KCH   196           // 784/4, per-wave K chunk

// d_ws byte layout
#define STATSF_OFF_B 0       // 110 f32
#define PART_OFF_B   512     // 65*1024 f32, [stat][block], 16B-aligned

#define ELT(v,c) ((c)==0?(v).x:((c)==1?(v).y:((c)==2?(v).z:(v).w)))

// ---------------- pass A: z0 = x@W0^T + b0 (K split across 4 waves) ----------------
__global__ __launch_bounds__(256, 4) void passA(const float* __restrict__ x,
                                                const float* __restrict__ W0,
                                                const float* __restrict__ b0,
                                                float* __restrict__ zout,
                                                float* __restrict__ partials) {
  __shared__ float comb[4][ROWS_PB][NF];
  const int tid = threadIdx.x;
  const int lane = tid & 63;
  const int wv = __builtin_amdgcn_readfirstlane(tid >> 6);   // scalar wave id

  const int rowbase = blockIdx.x * ROWS_PB;
  const int row = rowbase + lane;
  const float* xr = x + (size_t)row * DIN + wv * KCH;
  const float* wp = W0 + wv * KCH;                 // wave-uniform -> s_load

  float acc[NF];
#pragma unroll
  for (int j = 0; j < NF; ++j) acc[j] = (wv == 0) ? b0[j] : 0.f;

  float4 Aq[7], Bq[7];
#pragma unroll
  for (int q = 0; q < 7; ++q) Aq[q] = *(const float4*)(xr + q * 4);

#define BATCH(bi, CUR, NXT)                                                    \
  do {                                                                         \
    if ((bi) < 6) {                                                            \
      _Pragma("unroll") for (int q = 0; q < 7; ++q)                            \
          NXT[q] = *(const float4*)(xr + ((bi) + 1) * 28 + q * 4);             \
    }                                                                          \
    _Pragma("unroll") for (int e = 0; e < 28; ++e) {                           \
      float xv = ELT(CUR[(e) >> 2], (e)&3);                                    \
      _Pragma("unroll") for (int j = 0; j < NF; ++j)                           \
          acc[j] = fmaf(xv, wp[j * DIN + (bi)*28 + e], acc[j]);                \
    }                                                                          \
  } while (0)

  BATCH(0, Aq, Bq); BATCH(1, Bq, Aq); BATCH(2, Aq, Bq); BATCH(3, Bq, Aq);
  BATCH(4, Aq, Bq); BATCH(5, Bq, Aq); BATCH(6, Aq, Bq);
#undef BATCH

  // cross-wave combine (one barrier)
#pragma unroll
  for (int j = 0; j < NF; ++j) comb[wv][lane][j] = acc[j];
  __syncthreads();
  float a[NF];
#pragma unroll
  for (int j = 0; j < NF; ++j)
    a[j] = comb[0][lane][j] + comb[1][lane][j] + comb[2][lane][j] + comb[3][lane][j];

  if (wv == 0) {                  // z0 write (40B contiguous per lane)
    float* zr = zout + (size_t)row * NF;
#pragma unroll
    for (int j = 0; j < NF; j += 2) *(float2*)(zr + j) = make_float2(a[j], a[j + 1]);
  }

  // 65 moments; wave wv butterflies its subset only
  float vals[NSTAT];
  {
    int v = 0;
#pragma unroll
    for (int j = 0; j < NF; ++j) vals[v++] = a[j];
#pragma unroll
    for (int i = 0; i < NF; ++i)
#pragma unroll
      for (int j = i; j < NF; ++j) vals[v++] = a[i] * a[j];
  }
  const int kb2 = wv * 17, ke2 = (wv == 3) ? NSTAT : wv * 17 + 17;
#pragma unroll
  for (int k = 0; k < NSTAT; ++k) {
    if (k >= kb2 && k < ke2) {    // wave-uniform branch
      float s = vals[k];
#pragma unroll
      for (int m = 1; m < 64; m <<= 1) s += __shfl_xor(s, m, 64);
      if (lane == 0) partials[k * NB + blockIdx.x] = s;   // [stat][block]
    }
  }
}

// ---------------- pass B: 1-wave analytic BN recursion (f64 bootstrap, f32 loop) ----------------
__global__ __launch_bounds__(64, 1) void passB(const float* __restrict__ partials,
                                               const float* __restrict__ Ws,
                                               const float* __restrict__ g0,
                                               const float* __restrict__ gs,
                                               const float* __restrict__ betas,
                                               const float* __restrict__ Wfin,
                                               const float* __restrict__ bfin,
                                               float* __restrict__ statsf) {
  __shared__ double Sd[NSTAT];
  __shared__ float tb[2 * NF * NF];   // double-buffered transpose
  __shared__ float svl[2 * NF];       // double-buffered scale broadcast
  const int lane = threadIdx.x;
  const int il = lane < NF ? lane : NF - 1;   // clamped row id
  const bool owner = lane < NF;

  // phase 0: reduce partials (contiguous per lane, f64 accumulate)
  {
    const float* pr = partials + (size_t)lane * NB;
    double a0 = 0, a1 = 0, a2 = 0, a3 = 0;
    for (int b = 0; b < NB; b += 4) {
      float4 v = *(const float4*)(pr + b);
      a0 += v.x; a1 += v.y; a2 += v.z; a3 += v.w;
    }
    Sd[lane] = (a0 + a1) + (a2 + a3);
    if (lane == 0) {
      const float* p2 = partials + (size_t)64 * NB;
      double c0 = 0, c1 = 0, c2 = 0, c3 = 0;
      for (int b = 0; b < NB; b += 4) {
        float4 v = *(const float4*)(p2 + b);
        c0 += v.x; c1 += v.y; c2 += v.z; c3 += v.w;
      }
      Sd[64] = (c0 + c1) + (c2 + c3);
    }
  }
  __syncthreads();

  // bootstrap in f64: mu, Cov row, BN0 scale (cancellation lives here)
  const double invN = 1.0 / (double)NROWS;
  double mu[NF];
#pragma unroll
  for (int j = 0; j < NF; ++j) mu[j] = Sd[j] * invN;
  const double mu_own = Sd[il] * invN;

  const int idxd = NF + il * NF - (il * (il - 1)) / 2;
  double var_own = Sd[idxd] * invN - mu_own * mu_own;
  double s_own_d = (double)g0[il] / sqrt(var_own + 1e-5);
  if (owner) svl[NF + il] = (float)s_own_d;   // init uses slot 1 (k=0 uses slot 0)
  __syncthreads();
  float sjf[NF];
#pragma unroll
  for (int j = 0; j < NF; ++j) sjf[j] = svl[NF + j];

  float CovR[NF], Mrow[NF], dvv[NF];
#pragma unroll
  for (int j = 0; j < NF; ++j) {
    int a_ = il < j ? il : j, b_ = il < j ? j : il;
    int idx = NF + a_ * NF - (a_ * (a_ - 1)) / 2 + (b_ - a_);
    double cov = Sd[idx] * invN - mu_own * mu[j];
    CovR[j] = (float)(cov * s_own_d) * sjf[j];
    Mrow[j] = (il == j) ? (float)s_own_d : 0.f;
    dvv[j] = -(float)mu[j] * sjf[j];          // dv0 = -s0 .* mu0 (replicated)
  }

  for (int k = 0; k < NL; ++k) {
    const float* W = Ws + k * 100;             // uniform -> s_load
    const int sl = (k & 1) * NF * NF;
    const int ssl = (k & 1) * NF;

    // V = Cov * W^T  (row-local)
    float VR[NF];
#pragma unroll
    for (int l = 0; l < NF; ++l) {
      float t = 0.f;
#pragma unroll
      for (int m = 0; m < NF; ++m) t = fmaf(CovR[m], W[l * 10 + m], t);
      VR[l] = t;
    }
    if (owner) {
#pragma unroll
      for (int l = 0; l < NF; ++l) tb[sl + il * NF + l] = VR[l];
    }
    __syncthreads();                           // B1
    float YR[NF];                              // Y = V^T row  (valid: Cov symmetric)
#pragma unroll
    for (int l = 0; l < NF; ++l) YR[l] = tb[sl + l * NF + il];
    float CzR[NF];                             // Cz = W Cov W^T row
#pragma unroll
    for (int j = 0; j < NF; ++j) {
      float t = 0.f;
#pragma unroll
      for (int l = 0; l < NF; ++l) t = fmaf(YR[l], W[j * 10 + l], t);
      CzR[j] = t;
    }
    // diag extract + own scale
    float cz_own = CzR[0];
#pragma unroll
    for (int j = 1; j < NF; ++j) cz_own = (il == j) ? CzR[j] : cz_own;
    float s2 = gs[k * NF + il] / sqrtf(cz_own + 1e-5f);
    if (owner) svl[ssl + il] = s2;

    // barrier-shadow: M/dv matmuls are independent of s2
    float Pt[NF], Dt[NF];
#pragma unroll
    for (int j = 0; j < NF; ++j) {
      float t = 0.f, u = 0.f;
#pragma unroll
      for (int l = 0; l < NF; ++l) {
        t = fmaf(Mrow[l], W[j * 10 + l], t);
        u = fmaf(dvv[l], W[j * 10 + l], u);
      }
      Pt[j] = t; Dt[j] = u;
    }
    __syncthreads();                           // B2
#pragma unroll
    for (int j = 0; j < NF; ++j) sjf[j] = svl[ssl + j];
#pragma unroll
    for (int j = 0; j < NF; ++j) {
      CovR[j] = CzR[j] * s2 * sjf[j];
      Mrow[j] = Pt[j] * sjf[j];
      dvv[j] = Dt[j] * sjf[j];
    }
  }

  // final fold: Mf = M * Wf^T ; cf = bf + (dv + beta_last) Wf^T
  float cvecf[NF];
#pragma unroll
  for (int j = 0; j < NF; ++j) cvecf[j] = dvv[j] + betas[(NL - 1) * NF + j];
  float Ff[NF], cf[NF];
#pragma unroll
  for (int j = 0; j < NF; ++j) {
    float t = 0.f, u = bfin[j];
#pragma unroll
    for (int l = 0; l < NF; ++l) {
      t = fmaf(Mrow[l], Wfin[j * 10 + l], t);
      u = fmaf(cvecf[l], Wfin[j * 10 + l], u);
    }
    Ff[j] = t; cf[j] = u;
  }
  if (owner) {
#pragma unroll
    for (int j = 0; j < NF; ++j) statsf[il * NF + j] = Ff[j];
  }
  if (lane == 0) {
#pragma unroll
    for (int j = 0; j < NF; ++j) statsf[100 + j] = cf[j];
  }
}

// ---------------- pass C: out = z0 @ M + c (in place) ----------------
__global__ __launch_bounds__(256) void passC(float* __restrict__ z_inout,
                                             const float* __restrict__ statsf) {
  const int r = blockIdx.x * 256 + threadIdx.x;
  float* pz = z_inout + (size_t)r * NF;
  float zr[NF];
#pragma unroll
  for (int j = 0; j < NF; j += 2) {
    float2 v = *(const float2*)(pz + j);
    zr[j] = v.x; zr[j + 1] = v.y;
  }
  float acc2[NF];
#pragma unroll
  for (int j = 0; j < NF; ++j) acc2[j] = statsf[100 + j];
#pragma unroll
  for (int l = 0; l < NF; ++l)
#pragma unroll
    for (int j = 0; j < NF; ++j) acc2[j] = fmaf(zr[l], statsf[l * 10 + j], acc2[j]);
#pragma unroll
  for (int j = 0; j < NF; j += 2) *(float2*)(pz + j) = make_float2(acc2[j], acc2[j + 1]);
}

extern "C" void kernel_launch(void* const* d_in, const int* in_sizes, int n_in,
                              void* d_out, int out_size, void* d_ws, size_t ws_size,
                              hipStream_t stream) {
  const float* x     = (const float*)d_in[0];
  const float* W0    = (const float*)d_in[1];
  const float* b0    = (const float*)d_in[2];
  const float* g0    = (const float*)d_in[3];
  const float* Ws    = (const float*)d_in[5];
  const float* gs    = (const float*)d_in[7];
  const float* betas = (const float*)d_in[8];
  const float* Wfin  = (const float*)d_in[9];
  const float* bfin  = (const float*)d_in[10];
  float* out = (float*)d_out;
  // d_in[4]=beta0, d_in[6]=bs: provably cancel inside the BN algebra (see passB)

  float* statsf   = (float*)((char*)d_ws + STATSF_OFF_B);
  float* partials = (float*)((char*)d_ws + PART_OFF_B);

  passA<<<NB, 256, 0, stream>>>(x, W0, b0, out, partials);
  passB<<<1, 64, 0, stream>>>(partials, Ws, g0, gs, betas, Wfin, bfin, statsf);
  passC<<<256, 256, 0, stream>>>(out, statsf);
}

// Round 5
// 421.527 us; speedup vs baseline: 1.3316x; 1.3316x over previous
//
#include <hip/hip_runtime.h>

#define NROWS 65536
#define DIN   784
#define NF    10
#define NL    62
#define NSTAT 65
#define NB    1024          // passA grid = partials per stat
#define ROWS_PB 64
#define KCH   196           // 784/4, per-wave K chunk
#define TPW   7             // tiles per wave (196/28)

// d_ws byte layout
#define STATSF_OFF_B 0       // 110 f32
#define PART_OFF_B   512     // 65*1024 f32, [stat][block], 16B-aligned

#define KEEP4(v4) asm volatile("" : "+v"(v4.x), "+v"(v4.y), "+v"(v4.z), "+v"(v4.w))

// ---------------- pass A: z0 = x@W0^T + b0 ----------------
// 4 waves/block, each wave owns a K-quarter with its own LDS tile (no in-loop barriers)
__global__ __launch_bounds__(256, 2) void passA(const float* __restrict__ x,
                                                const float* __restrict__ W0,
                                                const float* __restrict__ b0,
                                                float* __restrict__ zout,
                                                float* __restrict__ partials) {
  __shared__ float xs[4 * 64 * 30];   // 4 per-wave 64x30 tiles (pad 30: 2-way alias, free)
  const int tid = threadIdx.x;
  const int lane = tid & 63;
  const int wv = __builtin_amdgcn_readfirstlane(tid >> 6);
  const int rowbase = blockIdx.x * ROWS_PB;

  const float* xw = x + (size_t)rowbase * DIN + wv * KCH;
  const float* wp = W0 + wv * KCH;            // wave-uniform -> s_load
  float* xsw = xs + wv * (64 * 30);

  int goff[TPW], soff[TPW];
#pragma unroll
  for (int q = 0; q < TPW; ++q) {
    int g = lane + q * 64;
    int row = g / 7, pos = g % 7;             // bijection [0,448) -> 64 rows x 7 slots
    goff[q] = row * DIN + pos * 4;
    soff[q] = row * 30 + pos * 4;
  }

  float acc[NF];
#pragma unroll
  for (int j = 0; j < NF; ++j) acc[j] = (wv == 0) ? b0[j] : 0.f;

  float4 Aq[TPW], Bq[TPW];
  // fill tile 0 (coalesced: 28 consecutive floats per row via 7 lanes)
#pragma unroll
  for (int q = 0; q < TPW; ++q) Aq[q] = *(const float4*)(xw + goff[q]);
#pragma unroll
  for (int q = 0; q < TPW; ++q) {
    float2* d = (float2*)(xsw + soff[q]);
    d[0] = make_float2(Aq[q].x, Aq[q].y);
    d[1] = make_float2(Aq[q].z, Aq[q].w);
  }

#define STEP(bi, NXT, DOLOAD)                                                  \
  do {                                                                         \
    if (DOLOAD) {                                                              \
      _Pragma("unroll") for (int q = 0; q < TPW; ++q)                          \
          NXT[q] = *(const float4*)(xw + ((bi) + 1) * 28 + goff[q]);           \
    }                                                                          \
    float xv[28];                                                              \
    _Pragma("unroll") for (int i = 0; i < 28; i += 2) {                        \
      float2 v = *(const float2*)(xsw + lane * 30 + i);                        \
      xv[i] = v.x; xv[i + 1] = v.y;                                            \
    }                                                                          \
    _Pragma("unroll") for (int e = 0; e < 28; ++e) {                           \
      _Pragma("unroll") for (int j = 0; j < NF; ++j)                           \
          acc[j] = fmaf(xv[e], wp[j * DIN + (bi)*28 + e], acc[j]);             \
    }                                                                          \
    if (DOLOAD) {                                                              \
      _Pragma("unroll") for (int q = 0; q < TPW; ++q) KEEP4(NXT[q]);           \
      _Pragma("unroll") for (int q = 0; q < TPW; ++q) {                        \
        float2* d = (float2*)(xsw + soff[q]);                                  \
        d[0] = make_float2(NXT[q].x, NXT[q].y);                                \
        d[1] = make_float2(NXT[q].z, NXT[q].w);                                \
      }                                                                        \
    }                                                                          \
  } while (0)

  STEP(0, Bq, 1); STEP(1, Aq, 1); STEP(2, Bq, 1);
  STEP(3, Aq, 1); STEP(4, Bq, 1); STEP(5, Aq, 1);
  STEP(6, Bq, 0);
#undef STEP

  // cross-wave combine: reuse xs as comb[4*64][10] (tiles dead after barrier)
  __syncthreads();
  float (*comb)[NF] = (float(*)[NF])xs;
#pragma unroll
  for (int j = 0; j < NF; ++j) comb[wv * 64 + lane][j] = acc[j];
  __syncthreads();
  float a[NF];
#pragma unroll
  for (int j = 0; j < NF; ++j)
    a[j] = comb[0 * 64 + lane][j] + comb[1 * 64 + lane][j] +
           comb[2 * 64 + lane][j] + comb[3 * 64 + lane][j];

  if (wv == 0) {                  // z0 write (40B contiguous per lane)
    float* zr = zout + (size_t)(rowbase + lane) * NF;
#pragma unroll
    for (int j = 0; j < NF; j += 2) *(float2*)(zr + j) = make_float2(a[j], a[j + 1]);
  }

  // 65 moments; wave wv butterflies its subset
  float vals[NSTAT];
  {
    int v = 0;
#pragma unroll
    for (int j = 0; j < NF; ++j) vals[v++] = a[j];
#pragma unroll
    for (int i = 0; i < NF; ++i)
#pragma unroll
      for (int j = i; j < NF; ++j) vals[v++] = a[i] * a[j];
  }
  const int kb2 = wv * 17, ke2 = (wv == 3) ? NSTAT : wv * 17 + 17;
#pragma unroll
  for (int k = 0; k < NSTAT; ++k) {
    if (k >= kb2 && k < ke2) {    // wave-uniform branch
      float s = vals[k];
#pragma unroll
      for (int m = 1; m < 64; m <<= 1) s += __shfl_xor(s, m, 64);
      if (lane == 0) partials[k * NB + blockIdx.x] = s;   // [stat][block]
    }
  }
}

// ---------------- pass B: 2-wave pipelined analytic BN recursion ----------------
// wave0: Cov spine (V -> LDS transpose -> Cz -> scales); wave1: M/dv chain.
// One barrier per layer; scales double-buffered in svl (slot (k+1)&1).
__global__ __launch_bounds__(128, 1) void passB(const float* __restrict__ partials,
                                                const float* __restrict__ Ws,
                                                const float* __restrict__ g0,
                                                const float* __restrict__ gs,
                                                const float* __restrict__ betas,
                                                const float* __restrict__ Wfin,
                                                const float* __restrict__ bfin,
                                                float* __restrict__ statsf) {
  __shared__ float WL[NL * 100];      // 24.8 KB: all layer weights
  __shared__ float gsl[NL * NF];
  __shared__ double Sd[NSTAT];
  __shared__ float tb[NF * NF];       // wave0-private transpose (within-wave ordered)
  __shared__ float svl[2 * NF];       // scale mailbox, double-buffered
  const int tid = threadIdx.x;
  const int lane = tid & 63;
  const int wv = __builtin_amdgcn_readfirstlane(tid >> 6);
  const int il = lane < NF ? lane : NF - 1;
  const bool owner = lane < NF;

  // stage all small params to LDS (coalesced)
  for (int i = tid; i < NL * 100; i += 128) WL[i] = Ws[i];
  for (int i = tid; i < NL * NF; i += 128) gsl[i] = gs[i];

  // phase 0: coalesced stat reduction (wave per stat-set, lane-strided)
  {
    const int k0 = (wv == 0) ? 0 : 33, k1 = (wv == 0) ? 33 : NSTAT;
    for (int k = k0; k < k1; ++k) {
      const float* pr = partials + (size_t)k * NB;
      double s = 0.0;
#pragma unroll
      for (int i = 0; i < NB / 64; ++i) s += (double)pr[i * 64 + lane];
#pragma unroll
      for (int m = 1; m < 64; m <<= 1) s += __shfl_xor(s, m, 64);
      if (lane == 0) Sd[k] = s;
    }
  }
  __syncthreads();

  const double invN = 1.0 / (double)NROWS;
  float s_own = 0.f;                  // wave0: own BN0 scale
  if (wv == 0) {
    const int idxd = NF + il * NF - (il * (il - 1)) / 2;
    double mu_own = Sd[il] * invN;
    double var_own = Sd[idxd] * invN - mu_own * mu_own;
    double s0d = (double)g0[il] / sqrt(var_own + 1e-5);
    s_own = (float)s0d;
    if (owner) svl[il] = s_own;       // scale-set 0 -> slot 0
  }
  __syncthreads();
  float sj0[NF];
#pragma unroll
  for (int j = 0; j < NF; ++j) sj0[j] = svl[j];

  // per-wave state
  float CovR[NF];                     // wave0: row il of scaled Cov
  float Mrow[NF], dvv[NF];            // wave1: row il of A, replicated dv
  if (wv == 0) {
    double mu_own = Sd[il] * invN;
#pragma unroll
    for (int j = 0; j < NF; ++j) {
      int a_ = il < j ? il : j, b_ = il < j ? j : il;
      int idx = NF + a_ * NF - (a_ * (a_ - 1)) / 2 + (b_ - a_);
      double cov = Sd[idx] * invN - mu_own * (Sd[j] * invN);
      CovR[j] = ((float)cov * s_own) * sj0[j];
    }
  } else {
#pragma unroll
    for (int j = 0; j < NF; ++j) {
      Mrow[j] = (il == j) ? sj0[j] : 0.f;
      dvv[j] = -(float)(Sd[j] * invN) * sj0[j];   // dv0 = -s0 .* mu0
    }
  }

  float CzR[NF], Pt[NF], Dt[NF], s2 = 0.f;
  for (int k = 0; k < NL; ++k) {
    const float* W = &WL[k * 100];
    if (wv == 0) {
      // V = Cov * W^T (row-local), stage to tb
      float VR[NF];
#pragma unroll
      for (int l = 0; l < NF; ++l) {
        float t = 0.f;
#pragma unroll
        for (int m = 0; m < NF; ++m) t = fmaf(CovR[m], W[l * 10 + m], t);
        VR[l] = t;
      }
      if (owner) {
        float2* d = (float2*)(tb + il * NF);
#pragma unroll
        for (int h = 0; h < 5; ++h) d[h] = make_float2(VR[2 * h], VR[2 * h + 1]);
      }
      // within-wave LDS write->read ordered; no barrier needed
      float YR[NF];
#pragma unroll
      for (int l = 0; l < NF; ++l) YR[l] = tb[l * NF + il];   // V^T row (Cov symmetric)
#pragma unroll
      for (int j = 0; j < NF; ++j) {
        float t = 0.f;
#pragma unroll
        for (int l = 0; l < NF; ++l) t = fmaf(YR[l], W[j * 10 + l], t);
        CzR[j] = t;                   // row of W Cov W^T
      }
      float cz_own = CzR[0];
#pragma unroll
      for (int j = 1; j < NF; ++j) cz_own = (il == j) ? CzR[j] : cz_own;
      s2 = gsl[k * NF + il] / sqrtf(cz_own + 1e-5f);
      if (owner) svl[((k + 1) & 1) * NF + il] = s2;   // scale-set k+1
    } else {
      // M/dv matmul with W_k (independent of new scales)
#pragma unroll
      for (int j = 0; j < NF; ++j) {
        float t = 0.f, u = 0.f;
#pragma unroll
        for (int l = 0; l < NF; ++l) {
          t = fmaf(Mrow[l], W[j * 10 + l], t);
          u = fmaf(dvv[l], W[j * 10 + l], u);
        }
        Pt[j] = t; Dt[j] = u;
      }
    }
    __syncthreads();                  // publish scale-set k+1
    float sjn[NF];
#pragma unroll
    for (int j = 0; j < NF; ++j) sjn[j] = svl[((k + 1) & 1) * NF + j];
    if (wv == 0) {
#pragma unroll
      for (int j = 0; j < NF; ++j) CovR[j] = CzR[j] * s2 * sjn[j];
    } else {
#pragma unroll
      for (int j = 0; j < NF; ++j) { Mrow[j] = Pt[j] * sjn[j]; dvv[j] = Dt[j] * sjn[j]; }
    }
  }

  // final fold on wave1: Mf = A * Wf^T ; cf = bf + (dv + beta_last) Wf^T
  if (wv == 1) {
    float cvecf[NF];
#pragma unroll
    for (int j = 0; j < NF; ++j) cvecf[j] = dvv[j] + betas[(NL - 1) * NF + j];
    float Ff[NF], cf[NF];
#pragma unroll
    for (int j = 0; j < NF; ++j) {
      float t = 0.f, u = bfin[j];
#pragma unroll
      for (int l = 0; l < NF; ++l) {
        t = fmaf(Mrow[l], Wfin[j * 10 + l], t);
        u = fmaf(cvecf[l], Wfin[j * 10 + l], u);
      }
      Ff[j] = t; cf[j] = u;
    }
    if (owner) {
#pragma unroll
      for (int j = 0; j < NF; ++j) statsf[il * NF + j] = Ff[j];
    }
    if (lane == 0) {
#pragma unroll
      for (int j = 0; j < NF; ++j) statsf[100 + j] = cf[j];
    }
  }
}

// ---------------- pass C: out = z0 @ M + c (in place) ----------------
__global__ __launch_bounds__(256) void passC(float* __restrict__ z_inout,
                                             const float* __restrict__ statsf) {
  const int r = blockIdx.x * 256 + threadIdx.x;
  float* pz = z_inout + (size_t)r * NF;
  float zr[NF];
#pragma unroll
  for (int j = 0; j < NF; j += 2) {
    float2 v = *(const float2*)(pz + j);
    zr[j] = v.x; zr[j + 1] = v.y;
  }
  float acc2[NF];
#pragma unroll
  for (int j = 0; j < NF; ++j) acc2[j] = statsf[100 + j];
#pragma unroll
  for (int l = 0; l < NF; ++l)
#pragma unroll
    for (int j = 0; j < NF; ++j) acc2[j] = fmaf(zr[l], statsf[l * 10 + j], acc2[j]);
#pragma unroll
  for (int j = 0; j < NF; j += 2) *(float2*)(pz + j) = make_float2(acc2[j], acc2[j + 1]);
}

extern "C" void kernel_launch(void* const* d_in, const int* in_sizes, int n_in,
                              void* d_out, int out_size, void* d_ws, size_t ws_size,
                              hipStream_t stream) {
  const float* x     = (const float*)d_in[0];
  const float* W0    = (const float*)d_in[1];
  const float* b0    = (const float*)d_in[2];
  const float* g0    = (const float*)d_in[3];
  const float* Ws    = (const float*)d_in[5];
  const float* gs    = (const float*)d_in[7];
  const float* betas = (const float*)d_in[8];
  const float* Wfin  = (const float*)d_in[9];
  const float* bfin  = (const float*)d_in[10];
  float* out = (float*)d_out;
  // d_in[4]=beta0, d_in[6]=bs cancel exactly inside the BN algebra (see passB derivation)

  float* statsf   = (float*)((char*)d_ws + STATSF_OFF_B);
  float* partials = (float*)((char*)d_ws + PART_OFF_B);

  passA<<<NB, 256, 0, stream>>>(x, W0, b0, out, partials);
  passB<<<1, 128, 0, stream>>>(partials, Ws, g0, gs, betas, Wfin, bfin, statsf);
  passC<<<256, 256, 0, stream>>>(out, statsf);
}